// Round 1
// baseline (4522.332 us; speedup 1.0000x reference)
//
#include <hip/hip_runtime.h>
#include <hip/hip_bf16.h>
#include <cstdint>

// LSTM (relu activations), B=128 T=256 F=4 H=1024, gate order i,f,g,o.
// Persistent kernel: 256 WGs = 4 row-blocks (32 rows) x 64 hidden-blocks (16 units).
// U slice (1024K x 64 gate-cols) held as bf16 MFMA B-fragments in VGPRs for all steps.
// Per step: each wave owns a K-quarter, MFMA 16x16x32 bf16, K-split partials reduced
// in LDS, fp32 gate math (x*W+b exact fp32), h exchanged via global bf16 double buffer,
// per-cluster (64 WG) monotonic atomic barrier with agent fences (cross-XCD safe).

#define B_SZ   128
#define T_SZ   256
#define H_SZ   1024
#define G_SZ   4096   // 4*H

typedef __attribute__((ext_vector_type(8))) short short8;
typedef __attribute__((ext_vector_type(4))) float f32x4;

__device__ __forceinline__ short f2bf(float f) {
    union { float f; unsigned u; } a; a.f = f;
    unsigned r = a.u + 0x7fffu + ((a.u >> 16) & 1u);   // RNE
    return (short)(r >> 16);
}

__device__ __forceinline__ float sigmoidf_(float x) {
    return 1.0f / (1.0f + __expf(-x));
}

__global__ __launch_bounds__(256, 1)
void lstm_persistent(const float* __restrict__ x, const float* __restrict__ W,
                     const float* __restrict__ U, const float* __restrict__ bias,
                     float* __restrict__ out, unsigned* __restrict__ cnt_base,
                     unsigned short* __restrict__ hbuf)
{
    __shared__ __align__(16) char smem[32768];
    short* Ust  = (short*)smem;   // init staging: [256 k][64 cols] bf16
    float* zpart = (float*)smem;  // per-step partials: [w][mt][g][16r][16c] fp32

    const int tid  = threadIdx.x;
    const int bid  = blockIdx.x;
    const int rb   = bid >> 6;    // row block 0..3  (rows rb*32 .. +32)
    const int jb   = bid & 63;    // hidden block 0..63 (units jb*16 .. +16)
    const int w    = tid >> 6;    // wave 0..3 -> K slice [w*256, w*256+256)
    const int lane = tid & 63;
    const int q    = lane >> 4;   // quad 0..3
    const int n    = lane & 15;

    // ---------- init: build persistent B fragments from U (fp32 -> bf16) ----------
    short8 bfrag[8][4];           // [kk (32-k chunk within wave slice)][gate]
    for (int kc = 0; kc < 4; ++kc) {
        const int kbase = kc * 256;
        for (int i = tid; i < 256 * 64; i += 256) {
            int k = i >> 6, col = i & 63;
            int gcol = (col >> 4) * 1024 + jb * 16 + (col & 15);
            Ust[k * 64 + col] = f2bf(U[(size_t)(kbase + k) * G_SZ + gcol]);
        }
        __syncthreads();
        if (w == kc) {
            #pragma unroll
            for (int kk = 0; kk < 8; ++kk) {
                #pragma unroll
                for (int g = 0; g < 4; ++g) {
                    short8 bb;
                    #pragma unroll
                    for (int jj = 0; jj < 8; ++jj)
                        bb[jj] = Ust[(kk * 32 + q * 8 + jj) * 64 + g * 16 + n];
                    bfrag[kk][g] = bb;
                }
            }
        }
        __syncthreads();
    }

    // ---------- per-thread epilogue constants ----------
    const int row_l  = tid >> 4;          // 0..15
    const int hid_l  = tid & 15;
    const int hid_g  = jb * 16 + hid_l;
    const int row_g0 = rb * 32 + row_l;   // pair 0 (mt=0)
    const int row_g1 = row_g0 + 16;       // pair 1 (mt=1)
    float Wr[4][4], br[4];
    #pragma unroll
    for (int g = 0; g < 4; ++g) {
        br[g] = bias[g * 1024 + hid_g];
        #pragma unroll
        for (int f = 0; f < 4; ++f)
            Wr[g][f] = W[(size_t)f * G_SZ + g * 1024 + hid_g];
    }
    float c0 = 0.f, c1 = 0.f;
    unsigned* cnt = cnt_base + rb * 32;   // 128B-separated per-cluster counters

    const int arow0 = rb * 32 + n;        // A-frag rows (mt 0/1 add 0/16)
    const int krow  = w * 256 + q * 8;

    // ---------- time loop ----------
    for (int t = 0; t < T_SZ; ++t) {
        const unsigned short* hsrc = hbuf + (size_t)(t & 1) * B_SZ * H_SZ;
        unsigned short*       hdst = hbuf + (size_t)((t + 1) & 1) * B_SZ * H_SZ;

        // A fragments: h[32 rows of rb][wave K-slice] from global (bf16)
        short8 af[8][2];
        #pragma unroll
        for (int kk = 0; kk < 8; ++kk) {
            #pragma unroll
            for (int mt = 0; mt < 2; ++mt) {
                const unsigned short* p =
                    hsrc + (size_t)(arow0 + mt * 16) * H_SZ + krow + kk * 32;
                af[kk][mt] = *(const short8*)p;
            }
        }

        f32x4 acc[2][4];
        #pragma unroll
        for (int mt = 0; mt < 2; ++mt)
            #pragma unroll
            for (int g = 0; g < 4; ++g)
                acc[mt][g] = (f32x4){0.f, 0.f, 0.f, 0.f};

        #pragma unroll
        for (int kk = 0; kk < 8; ++kk)
            #pragma unroll
            for (int mt = 0; mt < 2; ++mt)
                #pragma unroll
                for (int g = 0; g < 4; ++g)
                    acc[mt][g] = __builtin_amdgcn_mfma_f32_16x16x32_bf16(
                        af[kk][mt], bfrag[kk][g], acc[mt][g], 0, 0, 0);

        // K-split partials -> LDS  (C layout: row = q*4+v, col = n)
        #pragma unroll
        for (int mt = 0; mt < 2; ++mt)
            #pragma unroll
            for (int g = 0; g < 4; ++g)
                #pragma unroll
                for (int v = 0; v < 4; ++v)
                    zpart[(((w * 2 + mt) * 4 + g) * 16 + (q * 4 + v)) * 16 + n] =
                        acc[mt][g][v];
        __syncthreads();

        // ---------- epilogue: sum partials, add x*W+b, gates, state update ----------
        f32x4 xv0 = *(const f32x4*)(x + ((size_t)row_g0 * T_SZ + t) * 4);
        f32x4 xv1 = *(const f32x4*)(x + ((size_t)row_g1 * T_SZ + t) * 4);

        float hn0, hn1;
        {
            float z[4];
            #pragma unroll
            for (int g = 0; g < 4; ++g) {
                float s = br[g];
                #pragma unroll
                for (int ww = 0; ww < 4; ++ww)
                    s += zpart[(((ww * 2 + 0) * 4 + g) * 16 + row_l) * 16 + hid_l];
                s += xv0[0] * Wr[g][0] + xv0[1] * Wr[g][1] +
                     xv0[2] * Wr[g][2] + xv0[3] * Wr[g][3];
                z[g] = s;
            }
            float ig = sigmoidf_(z[0]), fg = sigmoidf_(z[1]);
            float gg = fmaxf(z[2], 0.f), og = sigmoidf_(z[3]);
            c0 = fg * c0 + ig * gg;
            hn0 = og * fmaxf(c0, 0.f);
        }
        {
            float z[4];
            #pragma unroll
            for (int g = 0; g < 4; ++g) {
                float s = br[g];
                #pragma unroll
                for (int ww = 0; ww < 4; ++ww)
                    s += zpart[(((ww * 2 + 1) * 4 + g) * 16 + row_l) * 16 + hid_l];
                s += xv1[0] * Wr[g][0] + xv1[1] * Wr[g][1] +
                     xv1[2] * Wr[g][2] + xv1[3] * Wr[g][3];
                z[g] = s;
            }
            float ig = sigmoidf_(z[0]), fg = sigmoidf_(z[1]);
            float gg = fmaxf(z[2], 0.f), og = sigmoidf_(z[3]);
            c1 = fg * c1 + ig * gg;
            hn1 = og * fmaxf(c1, 0.f);
        }

        // write new h (bf16 double buffer) and fp32 output
        hdst[(size_t)row_g0 * H_SZ + hid_g] = (unsigned short)f2bf(hn0);
        hdst[(size_t)row_g1 * H_SZ + hid_g] = (unsigned short)f2bf(hn1);
        out[((size_t)row_g0 * T_SZ + t) * H_SZ + hid_g] = hn0;
        out[((size_t)row_g1 * T_SZ + t) * H_SZ + hid_g] = hn1;
        if (t == T_SZ - 1) {
            float* hlast = out + (size_t)B_SZ * T_SZ * H_SZ;
            float* clast = hlast + (size_t)B_SZ * H_SZ;
            hlast[(size_t)row_g0 * H_SZ + hid_g] = hn0;
            hlast[(size_t)row_g1 * H_SZ + hid_g] = hn1;
            clast[(size_t)row_g0 * H_SZ + hid_g] = c0;
            clast[(size_t)row_g1 * H_SZ + hid_g] = c1;
        }

        // ---------- per-cluster barrier (64 WGs sharing this row block) ----------
        __syncthreads();   // all h stores drained (vmcnt(0) before s_barrier)
        if (t != T_SZ - 1) {
            if (tid == 0) {
                __threadfence();   // release: flush this XCD's L2 to LLC
                __hip_atomic_fetch_add(cnt, 1u, __ATOMIC_RELAXED,
                                       __HIP_MEMORY_SCOPE_AGENT);
                const unsigned target = 64u * (unsigned)(t + 1);
                while (__hip_atomic_load(cnt, __ATOMIC_RELAXED,
                                         __HIP_MEMORY_SCOPE_AGENT) < target)
                    __builtin_amdgcn_s_sleep(1);
                __threadfence();   // acquire: invalidate L1/L2 before reading new h
            }
            __syncthreads();
        }
    }
}

extern "C" void kernel_launch(void* const* d_in, const int* in_sizes, int n_in,
                              void* d_out, int out_size, void* d_ws, size_t ws_size,
                              hipStream_t stream) {
    const float* x    = (const float*)d_in[0];  // [128][256][4]
    const float* W    = (const float*)d_in[1];  // [4][4096]
    const float* U    = (const float*)d_in[2];  // [1024][4096]
    const float* bias = (const float*)d_in[3];  // [4096]
    float* out = (float*)d_out;                 // [128][256][1024] ++ h_last ++ c_last

    unsigned* cnt = (unsigned*)d_ws;                             // 4 counters, 128B apart
    unsigned short* hbuf = (unsigned short*)((char*)d_ws + 1024); // [2][128][1024] bf16

    // zero the barrier counters and h0 buffer (ws is poisoned 0xAA each run)
    hipMemsetAsync(d_ws, 0, 1024 + (size_t)B_SZ * H_SZ * 2, stream);

    hipLaunchKernelGGL(lstm_persistent, dim3(256), dim3(256), 0, stream,
                       x, W, U, bias, out, cnt, hbuf);
}

// Round 2
// 2804.400 us; speedup vs baseline: 1.6126x; 1.6126x over previous
//
#include <hip/hip_runtime.h>
#include <hip/hip_bf16.h>
#include <cstdint>

// LSTM (relu activations), B=128 T=256 F=4 H=1024, gate order i,f,g,o.
// Persistent kernel: 256 WGs = 4 row-blocks (32 rows) x 64 hidden-blocks (16 units).
// U slice held as bf16 MFMA B-fragments in VGPRs for all 256 steps.
// h exchange: out[b][t][:] IS h_t. Producers store fp32 with relaxed AGENT atomic
// stores (sc1 write-through to LLC, NO fences). Consumers use plain cached loads —
// safe because each step's h is at a fresh address (never cached pre-production;
// kernel-start acquire cleared pre-launch poison), so L2 serves the 64x reuse.
// Barrier: per-cluster flag vector (flags[rb][jb] = t+1, monotonic), wave0 polls
// all 64 flags lane-parallel with __all. Zero cache-maintenance ops in steady state.

#define B_SZ   128
#define T_SZ   256
#define H_SZ   1024
#define G_SZ   4096   // 4*H

typedef __attribute__((ext_vector_type(8))) short short8;
typedef __attribute__((ext_vector_type(4))) float f32x4;

__device__ __forceinline__ short f2bf(float f) {
    union { float f; unsigned u; } a; a.f = f;
    unsigned r = a.u + 0x7fffu + ((a.u >> 16) & 1u);   // RNE
    return (short)(r >> 16);
}

__device__ __forceinline__ float sigmoidf_(float x) {
    return 1.0f / (1.0f + __expf(-x));
}

// 8 fp32 -> short8 bf16 (round half-up via +0x8000, pack hi16 pairs with v_perm)
__device__ __forceinline__ short8 pack8(f32x4 a, f32x4 b) {
    union { f32x4 v; unsigned u[4]; } ua, ub; ua.v = a; ub.v = b;
    union { short8 s; unsigned d[4]; } r;
    r.d[0] = __builtin_amdgcn_perm(ua.u[1] + 0x8000u, ua.u[0] + 0x8000u, 0x07060302u);
    r.d[1] = __builtin_amdgcn_perm(ua.u[3] + 0x8000u, ua.u[2] + 0x8000u, 0x07060302u);
    r.d[2] = __builtin_amdgcn_perm(ub.u[1] + 0x8000u, ub.u[0] + 0x8000u, 0x07060302u);
    r.d[3] = __builtin_amdgcn_perm(ub.u[3] + 0x8000u, ub.u[2] + 0x8000u, 0x07060302u);
    return r.s;
}

__global__ __launch_bounds__(256, 1)
void lstm_persistent(const float* __restrict__ x, const float* __restrict__ W,
                     const float* __restrict__ U, const float* __restrict__ bias,
                     float* __restrict__ out, unsigned* __restrict__ flags)
{
    __shared__ __align__(16) char smem[32768];
    short* Ust   = (short*)smem;  // init staging: [256 k][64 cols] bf16
    float* zpart = (float*)smem;  // per-step partials: [w][mt][g][16r][16c] fp32

    const int tid  = threadIdx.x;
    const int bid  = blockIdx.x;
    const int rb   = bid >> 6;    // row block 0..3  (rows rb*32 .. +32)
    const int jb   = bid & 63;    // hidden block 0..63 (units jb*16 .. +16)
    const int w    = tid >> 6;    // wave 0..3 -> K slice [w*256, w*256+256)
    const int lane = tid & 63;
    const int q    = lane >> 4;   // quad 0..3
    const int n    = lane & 15;

    // ---------- init: build persistent B fragments from U (fp32 -> bf16) ----------
    short8 bfrag[8][4];           // [kk (32-k chunk within wave slice)][gate]
    for (int kc = 0; kc < 4; ++kc) {
        const int kbase = kc * 256;
        for (int i = tid; i < 256 * 64; i += 256) {
            int k = i >> 6, col = i & 63;
            int gcol = (col >> 4) * 1024 + jb * 16 + (col & 15);
            Ust[k * 64 + col] = f2bf(U[(size_t)(kbase + k) * G_SZ + gcol]);
        }
        __syncthreads();
        if (w == kc) {
            #pragma unroll
            for (int kk = 0; kk < 8; ++kk) {
                #pragma unroll
                for (int g = 0; g < 4; ++g) {
                    short8 bb;
                    #pragma unroll
                    for (int jj = 0; jj < 8; ++jj)
                        bb[jj] = Ust[(kk * 32 + q * 8 + jj) * 64 + g * 16 + n];
                    bfrag[kk][g] = bb;
                }
            }
        }
        __syncthreads();
    }

    // ---------- per-thread epilogue constants ----------
    const int row_l  = tid >> 4;          // 0..15
    const int hid_l  = tid & 15;
    const int hid_g  = jb * 16 + hid_l;
    const int row_g0 = rb * 32 + row_l;   // pair 0 (mt=0)
    const int row_g1 = row_g0 + 16;       // pair 1 (mt=1)
    float Wr[4][4], br[4];
    #pragma unroll
    for (int g = 0; g < 4; ++g) {
        br[g] = bias[g * 1024 + hid_g];
        #pragma unroll
        for (int f = 0; f < 4; ++f)
            Wr[g][f] = W[(size_t)f * G_SZ + g * 1024 + hid_g];
    }
    float c0 = 0.f, c1 = 0.f;

    const int arow0 = rb * 32 + n;        // A-frag rows (mt 0/1 add 0/16)
    const int krow  = w * 256 + q * 8;
    unsigned* myflags = flags + rb * 64;  // 64 flags per cluster

    // ---------- time loop ----------
    for (int t = 0; t < T_SZ; ++t) {
        // A fragments: h_{t-1} = out[.][t-1][.] (fp32, plain cached loads), cvt to bf16
        short8 af[8][2];
        if (t == 0) {
            short8 z = {};
            #pragma unroll
            for (int kk = 0; kk < 8; ++kk) { af[kk][0] = z; af[kk][1] = z; }
        } else {
            #pragma unroll
            for (int kk = 0; kk < 8; ++kk) {
                #pragma unroll
                for (int mt = 0; mt < 2; ++mt) {
                    const float* p = out +
                        ((size_t)(arow0 + mt * 16) * T_SZ + (t - 1)) * H_SZ +
                        krow + kk * 32;
                    f32x4 lo = *(const f32x4*)p;
                    f32x4 hi = *(const f32x4*)(p + 4);
                    af[kk][mt] = pack8(lo, hi);
                }
            }
        }

        f32x4 acc[2][4];
        #pragma unroll
        for (int mt = 0; mt < 2; ++mt)
            #pragma unroll
            for (int g = 0; g < 4; ++g)
                acc[mt][g] = (f32x4){0.f, 0.f, 0.f, 0.f};

        #pragma unroll
        for (int kk = 0; kk < 8; ++kk)
            #pragma unroll
            for (int mt = 0; mt < 2; ++mt)
                #pragma unroll
                for (int g = 0; g < 4; ++g)
                    acc[mt][g] = __builtin_amdgcn_mfma_f32_16x16x32_bf16(
                        af[kk][mt], bfrag[kk][g], acc[mt][g], 0, 0, 0);

        // K-split partials -> LDS  (C layout: row = q*4+v, col = n)
        #pragma unroll
        for (int mt = 0; mt < 2; ++mt)
            #pragma unroll
            for (int g = 0; g < 4; ++g)
                #pragma unroll
                for (int v = 0; v < 4; ++v)
                    zpart[(((w * 2 + mt) * 4 + g) * 16 + (q * 4 + v)) * 16 + n] =
                        acc[mt][g][v];
        __syncthreads();

        // ---------- epilogue: sum partials, add x*W+b, gates, state update ----------
        f32x4 xv0 = *(const f32x4*)(x + ((size_t)row_g0 * T_SZ + t) * 4);
        f32x4 xv1 = *(const f32x4*)(x + ((size_t)row_g1 * T_SZ + t) * 4);

        float hn0, hn1;
        {
            float z[4];
            #pragma unroll
            for (int g = 0; g < 4; ++g) {
                float s = br[g];
                #pragma unroll
                for (int ww = 0; ww < 4; ++ww)
                    s += zpart[(((ww * 2 + 0) * 4 + g) * 16 + row_l) * 16 + hid_l];
                s += xv0[0] * Wr[g][0] + xv0[1] * Wr[g][1] +
                     xv0[2] * Wr[g][2] + xv0[3] * Wr[g][3];
                z[g] = s;
            }
            float ig = sigmoidf_(z[0]), fg = sigmoidf_(z[1]);
            float gg = fmaxf(z[2], 0.f), og = sigmoidf_(z[3]);
            c0 = fg * c0 + ig * gg;
            hn0 = og * fmaxf(c0, 0.f);
        }
        {
            float z[4];
            #pragma unroll
            for (int g = 0; g < 4; ++g) {
                float s = br[g];
                #pragma unroll
                for (int ww = 0; ww < 4; ++ww)
                    s += zpart[(((ww * 2 + 1) * 4 + g) * 16 + row_l) * 16 + hid_l];
                s += xv1[0] * Wr[g][0] + xv1[1] * Wr[g][1] +
                     xv1[2] * Wr[g][2] + xv1[3] * Wr[g][3];
                z[g] = s;
            }
            float ig = sigmoidf_(z[0]), fg = sigmoidf_(z[1]);
            float gg = fmaxf(z[2], 0.f), og = sigmoidf_(z[3]);
            c1 = fg * c1 + ig * gg;
            hn1 = og * fmaxf(c1, 0.f);
        }

        // h_t -> out[b][t][:] via agent-scope (sc1, write-through) atomic stores
        __hip_atomic_store((unsigned*)&out[((size_t)row_g0 * T_SZ + t) * H_SZ + hid_g],
                           __float_as_uint(hn0), __ATOMIC_RELAXED,
                           __HIP_MEMORY_SCOPE_AGENT);
        __hip_atomic_store((unsigned*)&out[((size_t)row_g1 * T_SZ + t) * H_SZ + hid_g],
                           __float_as_uint(hn1), __ATOMIC_RELAXED,
                           __HIP_MEMORY_SCOPE_AGENT);
        if (t == T_SZ - 1) {
            float* hlast = out + (size_t)B_SZ * T_SZ * H_SZ;
            float* clast = hlast + (size_t)B_SZ * H_SZ;
            hlast[(size_t)row_g0 * H_SZ + hid_g] = hn0;
            hlast[(size_t)row_g1 * H_SZ + hid_g] = hn1;
            clast[(size_t)row_g0 * H_SZ + hid_g] = c0;
            clast[(size_t)row_g1 * H_SZ + hid_g] = c1;
        }

        // ---------- per-cluster flag barrier (64 WGs sharing this row block) ----------
        __syncthreads();   // drains vmcnt: all sc1 h-stores acked at LLC
        if (t != T_SZ - 1) {
            if (tid == 0)
                __hip_atomic_store(&myflags[jb], (unsigned)(t + 1),
                                   __ATOMIC_RELAXED, __HIP_MEMORY_SCOPE_AGENT);
            if (tid < 64) {
                const unsigned tgt = (unsigned)(t + 1);
                for (;;) {
                    unsigned v = __hip_atomic_load(&myflags[tid], __ATOMIC_RELAXED,
                                                   __HIP_MEMORY_SCOPE_AGENT);
                    if (__all((int)(v >= tgt))) break;
                    __builtin_amdgcn_s_sleep(2);
                }
            }
            __atomic_signal_fence(__ATOMIC_ACQUIRE);  // compiler-only ordering
            __syncthreads();
        }
    }
}

extern "C" void kernel_launch(void* const* d_in, const int* in_sizes, int n_in,
                              void* d_out, int out_size, void* d_ws, size_t ws_size,
                              hipStream_t stream) {
    const float* x    = (const float*)d_in[0];  // [128][256][4]
    const float* W    = (const float*)d_in[1];  // [4][4096]
    const float* U    = (const float*)d_in[2];  // [1024][4096]
    const float* bias = (const float*)d_in[3];  // [4096]
    float* out = (float*)d_out;                 // [128][256][1024] ++ h_last ++ c_last

    unsigned* flags = (unsigned*)d_ws;          // [4 clusters][64] monotonic step flags

    // zero the flags (ws is poisoned 0xAA before every timed launch)
    hipMemsetAsync(d_ws, 0, 4 * 64 * sizeof(unsigned), stream);

    hipLaunchKernelGGL(lstm_persistent, dim3(256), dim3(256), 0, stream,
                       x, W, U, bias, out, flags);
}